// Round 1
// baseline (93979.980 us; speedup 1.0000x reference)
//
#include <hip/hip_runtime.h>
#include <stdint.h>
#include <math.h>

#define HID   1024
#define CHARD 512
#define NC    50257
#define TLEN  2048
#define NBH   1571   // head blocks: 32 rows each -> 50272 >= 50257

typedef unsigned long long ull;

__device__ __forceinline__ unsigned ford(float f) {
    unsigned b = __float_as_uint(f);
    return (b & 0x80000000u) ? ~b : (b | 0x80000000u);
}
__device__ __forceinline__ ull packkv(float v, unsigned j) {
    return ((ull)ford(v) << 32) | (ull)(0xFFFFFFFFu - j);
}
__device__ __forceinline__ ull umaxu(ull a, ull b) { return a > b ? a : b; }

// ---------------- init: h0 = inputs, c = 0, blockmax seeded so first argmax = start
__global__ __launch_bounds__(256) void k_init(const float* __restrict__ inputs,
                                              const int* __restrict__ startp,
                                              float* __restrict__ h0,
                                              float* __restrict__ c,
                                              ull* __restrict__ blockmax)
{
    int tid = blockIdx.x * 256 + threadIdx.x;
    if (tid < NBH) blockmax[tid] = (tid == 0) ? packkv(3.0e38f, (unsigned)startp[0]) : 0ull;
    if (tid < HID) { h0[tid] = inputs[tid]; c[tid] = 0.f; }
}

// ---------------- LSTM cell step. Also: reduce prev step's blockmax -> char, emit chars[t-1],
// and gather x = embed[char] into LDS.
__global__ __launch_bounds__(256) void k_lstm(const float* __restrict__ W_ih,
                                              const float* __restrict__ W_hh,
                                              const float* __restrict__ b_ih,
                                              const float* __restrict__ b_hh,
                                              const float* __restrict__ embed,
                                              const ull* __restrict__ blockmax,
                                              const float* __restrict__ h_in,
                                              float* __restrict__ h_out,
                                              float* __restrict__ c,
                                              float* __restrict__ chars_out,
                                              int t)
{
    __shared__ float4 xs4[CHARD / 4];   // 128
    __shared__ float4 hs4[HID / 4];     // 256
    __shared__ ull    red[256];

    const int tid = threadIdx.x;

    // ---- argmax of previous step (every block does it redundantly; 1571*8B from L2)
    ull pm = 0ull;
    for (int i = tid; i < NBH; i += 256) pm = umaxu(pm, blockmax[i]);
    red[tid] = pm;
    __syncthreads();
    for (int s = 128; s > 0; s >>= 1) {
        if (tid < s) red[tid] = umaxu(red[tid], red[tid + s]);
        __syncthreads();
    }
    const unsigned idx = 0xFFFFFFFFu - (unsigned)(red[0] & 0xFFFFFFFFull);
    if (t > 0 && blockIdx.x == 0 && tid == 0) chars_out[t - 1] = (float)idx;

    // ---- stage x = embed[idx] and h into LDS
    const float4* ex = (const float4*)(embed + (size_t)idx * CHARD);
    if (tid < 128) xs4[tid] = ex[tid];
    hs4[tid] = ((const float4*)h_in)[tid];
    __syncthreads();

    const int wave = tid >> 6;
    const int lane = tid & 63;
    const int r = blockIdx.x * 4 + wave;   // output element 0..1023

    float acc[4];
    #pragma unroll
    for (int q = 0; q < 4; ++q) {
        const float4* wi = (const float4*)(W_ih + (size_t)(q * HID + r) * CHARD);
        const float4* wh = (const float4*)(W_hh + (size_t)(q * HID + r) * HID);
        float a = 0.f;
        #pragma unroll
        for (int m = 0; m < 2; ++m) {
            float4 w = wi[m * 64 + lane], v = xs4[m * 64 + lane];
            a = fmaf(w.x, v.x, a); a = fmaf(w.y, v.y, a);
            a = fmaf(w.z, v.z, a); a = fmaf(w.w, v.w, a);
        }
        #pragma unroll
        for (int m = 0; m < 4; ++m) {
            float4 w = wh[m * 64 + lane], v = hs4[m * 64 + lane];
            a = fmaf(w.x, v.x, a); a = fmaf(w.y, v.y, a);
            a = fmaf(w.z, v.z, a); a = fmaf(w.w, v.w, a);
        }
        acc[q] = a;
    }

    #pragma unroll
    for (int q = 0; q < 4; ++q) {
        #pragma unroll
        for (int off = 32; off > 0; off >>= 1)
            acc[q] += __shfl_xor(acc[q], off);
    }

    if (lane == 0) {
        float zi = acc[0] + b_ih[r]           + b_hh[r];
        float zf = acc[1] + b_ih[HID + r]     + b_hh[HID + r];
        float zg = acc[2] + b_ih[2 * HID + r] + b_hh[2 * HID + r];
        float zo = acc[3] + b_ih[3 * HID + r] + b_hh[3 * HID + r];
        float ig = 1.f / (1.f + expf(-zi));
        float fg = 1.f / (1.f + expf(-zf));
        float gg = tanhf(zg);
        float og = 1.f / (1.f + expf(-zo));
        float cn = fg * c[r] + ig * gg;
        c[r] = cn;
        h_out[r] = og * tanhf(cn);
    }
}

// ---------------- head: logits = W_head @ h + b_head; per-block packed argmax -> blockmax
__global__ __launch_bounds__(256) void k_head(const float* __restrict__ W_head,
                                              const float* __restrict__ b_head,
                                              const float* __restrict__ h_in,
                                              float* __restrict__ logits,
                                              ull* __restrict__ blockmax)
{
    __shared__ float4 hs4[HID / 4];   // 256
    __shared__ ull    wmax[4];

    const int tid = threadIdx.x;
    hs4[tid] = ((const float4*)h_in)[tid];
    __syncthreads();

    const int wave = tid >> 6;
    const int lane = tid & 63;
    const int base = blockIdx.x * 32 + wave * 8;

    ull pm = 0ull;
    #pragma unroll
    for (int rep = 0; rep < 8; ++rep) {
        const int j = base + rep;
        if (j < NC) {
            const float4* w = (const float4*)(W_head + (size_t)j * HID);
            float a = 0.f;
            #pragma unroll
            for (int m = 0; m < 4; ++m) {
                float4 ww = w[m * 64 + lane], v = hs4[m * 64 + lane];
                a = fmaf(ww.x, v.x, a); a = fmaf(ww.y, v.y, a);
                a = fmaf(ww.z, v.z, a); a = fmaf(ww.w, v.w, a);
            }
            #pragma unroll
            for (int off = 32; off > 0; off >>= 1)
                a += __shfl_xor(a, off);
            const float v = a + b_head[j];
            if (lane == 0) __builtin_nontemporal_store(v, &logits[j]);
            pm = umaxu(pm, packkv(v, (unsigned)j));
        }
    }
    if (lane == 0) wmax[wave] = pm;
    __syncthreads();
    if (tid == 0)
        blockmax[blockIdx.x] = umaxu(umaxu(wmax[0], wmax[1]), umaxu(wmax[2], wmax[3]));
}

// ---------------- final: emit chars[T-1]
__global__ __launch_bounds__(256) void k_final(const ull* __restrict__ blockmax,
                                               float* __restrict__ chars_out)
{
    __shared__ ull red[256];
    const int tid = threadIdx.x;
    ull pm = 0ull;
    for (int i = tid; i < NBH; i += 256) pm = umaxu(pm, blockmax[i]);
    red[tid] = pm;
    __syncthreads();
    for (int s = 128; s > 0; s >>= 1) {
        if (tid < s) red[tid] = umaxu(red[tid], red[tid + s]);
        __syncthreads();
    }
    if (tid == 0)
        chars_out[TLEN - 1] = (float)(0xFFFFFFFFu - (unsigned)(red[0] & 0xFFFFFFFFull));
}

extern "C" void kernel_launch(void* const* d_in, const int* in_sizes, int n_in,
                              void* d_out, int out_size, void* d_ws, size_t ws_size,
                              hipStream_t stream)
{
    const float* inputs = (const float*)d_in[0];
    const float* embed  = (const float*)d_in[1];
    const float* W_ih   = (const float*)d_in[2];
    const float* W_hh   = (const float*)d_in[3];
    const float* b_ih   = (const float*)d_in[4];
    const float* b_hh   = (const float*)d_in[5];
    const float* W_head = (const float*)d_in[6];
    const float* b_head = (const float*)d_in[7];
    const int*   startp = (const int*)d_in[9];

    float* out        = (float*)d_out;
    float* chars_out  = out;          // [2048]
    float* logits_out = out + TLEN;   // [2048 * 50257]

    char* ws = (char*)d_ws;
    float* h0 = (float*)(ws);                 // 1024 f
    float* h1 = (float*)(ws + 4096);          // 1024 f
    float* c  = (float*)(ws + 8192);          // 1024 f
    ull* blockmax = (ull*)(ws + 12288);       // NBH ull

    hipLaunchKernelGGL(k_init, dim3(7), dim3(256), 0, stream,
                       inputs, startp, h0, c, blockmax);

    for (int t = 0; t < TLEN; ++t) {
        const float* hin = (t & 1) ? h1 : h0;
        float*       hout = (t & 1) ? h0 : h1;
        hipLaunchKernelGGL(k_lstm, dim3(256), dim3(256), 0, stream,
                           W_ih, W_hh, b_ih, b_hh, embed, blockmax,
                           hin, hout, c, chars_out, t);
        hipLaunchKernelGGL(k_head, dim3(NBH), dim3(256), 0, stream,
                           W_head, b_head, hout,
                           logits_out + (size_t)t * NC, blockmax);
    }
    hipLaunchKernelGGL(k_final, dim3(1), dim3(256), 0, stream, blockmax, chars_out);
}